// Round 1
// baseline (249.978 us; speedup 1.0000x reference)
//
#include <hip/hip_runtime.h>
#include <math.h>

// Problem constants (from reference)
#define N_USERS 100000
#define M_ITEMS 200000
#define K_DIM   128
#define P_DIM   (N_USERS + 2 * M_ITEMS)   // 500000
#define CAP     1024                       // max compacted nonzeros (actual: 52)

// Workspace layout (d_ws):
//   [0..3]              int   count      (must be zeroed each launch)
//   [16 .. 16+4*CAP)    int   eidx[CAP]
//   [16+4*CAP .. +4*CAP) float eval[CAP]

__global__ void scan_kernel(const float* __restrict__ x,
                            int* __restrict__ count,
                            int* __restrict__ eidx,
                            float* __restrict__ eval) {
    const int n4 = P_DIM / 4;  // 125000, P_DIM divisible by 4
    int i4 = blockIdx.x * blockDim.x + threadIdx.x;
    if (i4 >= n4) return;
    float4 v = reinterpret_cast<const float4*>(x)[i4];
    float a0 = v.x, a1 = v.y, a2 = v.z, a3 = v.w;
    // branchy append is fine: ~52 hits total across the whole grid
    if (a0 != 0.0f) { int p = atomicAdd(count, 1); if (p < CAP) { eidx[p] = 4*i4 + 0; eval[p] = a0; } }
    if (a1 != 0.0f) { int p = atomicAdd(count, 1); if (p < CAP) { eidx[p] = 4*i4 + 1; eval[p] = a1; } }
    if (a2 != 0.0f) { int p = atomicAdd(count, 1); if (p < CAP) { eidx[p] = 4*i4 + 2; eval[p] = a2; } }
    if (a3 != 0.0f) { int p = atomicAdd(count, 1); if (p < CAP) { eidx[p] = 4*i4 + 3; eval[p] = a3; } }
}

__global__ void finish_kernel(const int* __restrict__ count,
                              const int* __restrict__ eidx,
                              const float* __restrict__ eval,
                              const float* __restrict__ w0,
                              const float* __restrict__ delta,
                              const float* __restrict__ w_bias,
                              const float* __restrict__ uV,
                              const float* __restrict__ tV,
                              const float* __restrict__ bV,
                              float* __restrict__ out) {
    const int tid = threadIdx.x;  // K_DIM = 128 threads; tid = k-component
    int cnt = *count;
    if (cnt > CAP) cnt = CAP;

    float u = 0.0f, t = 0.0f, s = 0.0f, sq = 0.0f, bias = 0.0f;
    for (int e = 0; e < cnt; ++e) {
        const int   idx = eidx[e];   // uniform across block -> scalar-cached
        const float val = eval[e];
        if (tid == 0) bias += val * w_bias[idx];
        if (idx < N_USERS) {
            u += val * uV[(size_t)idx * K_DIM + tid];
        } else if (idx < N_USERS + M_ITEMS) {
            t += val * tV[(size_t)(idx - N_USERS) * K_DIM + tid];
        } else {
            float b = bV[(size_t)(idx - N_USERS - M_ITEMS) * K_DIM + tid];
            s  += val * b;
            sq += val * b * b;   // xb @ (b_V*b_V) summed over k
        }
    }

    // Reduce 5 dot products across 128 threads
    __shared__ float sh[5][K_DIM];
    sh[0][tid] = u * t;   // u_t
    sh[1][tid] = t * s;   // t_b
    sh[2][tid] = s * s;   // ||s||^2
    sh[3][tid] = u * s;   // u_b
    sh[4][tid] = sq;      // sq_sum
    __syncthreads();
    for (int off = K_DIM / 2; off > 0; off >>= 1) {
        if (tid < off) {
            #pragma unroll
            for (int j = 0; j < 5; ++j) sh[j][tid] += sh[j][tid + off];
        }
        __syncthreads();
    }

    if (tid == 0) {
        const float ut = sh[0][0], tb = sh[1][0], ss = sh[2][0],
                    ub = sh[3][0], sqs = sh[4][0];
        const float bs = 0.5f * (ss - sqs);
        // GAMMA = (1,1,1,1)
        float y = w0[0] + bias + ut + tb + bs + ub;
        float z = y * delta[0];
        // -log_sigmoid(z) = softplus(-z), numerically stable
        float a = -z;
        out[0] = fmaxf(a, 0.0f) + log1pf(expf(-fabsf(a)));
    }
}

extern "C" void kernel_launch(void* const* d_in, const int* in_sizes, int n_in,
                              void* d_out, int out_size, void* d_ws, size_t ws_size,
                              hipStream_t stream) {
    const float* x      = (const float*)d_in[0];
    const float* delta  = (const float*)d_in[1];
    // d_in[2] = pmi, unused by the reference
    const float* w0     = (const float*)d_in[3];
    const float* w_bias = (const float*)d_in[4];
    const float* uV     = (const float*)d_in[5];
    const float* tV     = (const float*)d_in[6];
    const float* bV     = (const float*)d_in[7];
    float* out = (float*)d_out;

    int*   count = (int*)d_ws;
    int*   eidx  = (int*)((char*)d_ws + 16);
    float* eval  = (float*)((char*)d_ws + 16 + CAP * sizeof(int));

    hipMemsetAsync(d_ws, 0, 16, stream);  // zero the atomic counter (ws is poisoned)

    const int n4 = P_DIM / 4;
    const int blocks = (n4 + 255) / 256;
    scan_kernel<<<blocks, 256, 0, stream>>>(x, count, eidx, eval);
    finish_kernel<<<1, K_DIM, 0, stream>>>(count, eidx, eval, w0, delta,
                                           w_bias, uV, tV, bV, out);
}

// Round 2
// 207.843 us; speedup vs baseline: 1.2027x; 1.2027x over previous
//
#include <hip/hip_runtime.h>
#include <math.h>

// Problem constants (from reference)
#define N_USERS 100000
#define M_ITEMS 200000
#define K_DIM   128
#define P_DIM   (N_USERS + 2 * M_ITEMS)   // 500000
#define N4      (P_DIM / 4)               // 125000 float4s
#define SCAN_T  256
#define SCAN_BLOCKS ((N4 + SCAN_T - 1) / SCAN_T)  // 489
#define SLOTS   64                         // max nonzeros per 1024-elem window
#define MAXNZ   256                        // max total nonzeros (actual: 52)

// Workspace layout (d_ws) — every word we read is written first this launch,
// so no zero-init needed (ws is poisoned 0xAA by the harness):
//   [0 .. 4*SCAN_BLOCKS)        int   counts[SCAN_BLOCKS]
//   [4096 .. +4*SCAN_BLOCKS*SLOTS)   int   gidx[SCAN_BLOCKS*SLOTS]
//   then                             float gval[SCAN_BLOCKS*SLOTS]

__global__ __launch_bounds__(SCAN_T) void scan_kernel(
        const float* __restrict__ x,
        int* __restrict__ counts,
        int* __restrict__ gidx,
        float* __restrict__ gval) {
    __shared__ int lc;
    __shared__ int   lidx[SLOTS];
    __shared__ float lval[SLOTS];
    const int tid = threadIdx.x;
    const int b   = blockIdx.x;
    if (tid == 0) lc = 0;
    __syncthreads();

    const int i4 = b * SCAN_T + tid;
    if (i4 < N4) {
        float4 v = reinterpret_cast<const float4*>(x)[i4];
        float a[4] = {v.x, v.y, v.z, v.w};
        #pragma unroll
        for (int j = 0; j < 4; ++j) {
            if (a[j] != 0.0f) {
                int p = atomicAdd(&lc, 1);
                if (p < SLOTS) { lidx[p] = 4 * i4 + j; lval[p] = a[j]; }
            }
        }
    }
    __syncthreads();
    int c = lc; if (c > SLOTS) c = SLOTS;
    if (tid == 0) counts[b] = c;
    if (tid < c) {
        gidx[b * SLOTS + tid] = lidx[tid];
        gval[b * SLOTS + tid] = lval[tid];
    }
}

__global__ __launch_bounds__(1024) void finish_kernel(
        const int* __restrict__ counts,
        const int* __restrict__ gidx,
        const float* __restrict__ gval,
        const float* __restrict__ w0,
        const float* __restrict__ delta,
        const float* __restrict__ w_bias,
        const float* __restrict__ uV,
        const float* __restrict__ tV,
        const float* __restrict__ bV,
        float* __restrict__ out) {
    const int tid = threadIdx.x;

    __shared__ int   lcnt;
    __shared__ int   lidx[MAXNZ];
    __shared__ float lval[MAXNZ];
    __shared__ float sb[MAXNZ];                 // bias partials
    __shared__ float pu[8][K_DIM], pt[8][K_DIM], ps[8][K_DIM], psq[8][K_DIM];
    __shared__ float red[5][K_DIM];

    if (tid == 0) lcnt = 0;
    __syncthreads();

    // Phase A: compact per-scan-block lists into one LDS list (parallel)
    if (tid < SCAN_BLOCKS) {
        int cb = counts[tid];
        for (int j = 0; j < cb; ++j) {
            int p = atomicAdd(&lcnt, 1);
            if (p < MAXNZ) {
                lidx[p] = gidx[tid * SLOTS + j];
                lval[p] = gval[tid * SLOTS + j];
            }
        }
    }
    __syncthreads();
    int cnt = lcnt; if (cnt > MAXNZ) cnt = MAXNZ;

    // Phase B1: bias gather — one thread per event, fully parallel
    if (tid < MAXNZ)
        sb[tid] = (tid < cnt) ? lval[tid] * w_bias[lidx[tid]] : 0.0f;

    // Phase B2: row gathers — 8 k-slices, events strided across slices
    const int k  = tid & (K_DIM - 1);
    const int sl = tid >> 7;   // 0..7
    float u = 0.0f, t = 0.0f, s = 0.0f, sq = 0.0f;
    for (int e = sl; e < cnt; e += 8) {
        const int   idx = lidx[e];
        const float val = lval[e];
        if (idx < N_USERS) {
            u += val * uV[(size_t)idx * K_DIM + k];
        } else if (idx < N_USERS + M_ITEMS) {
            t += val * tV[(size_t)(idx - N_USERS) * K_DIM + k];
        } else {
            float b = bV[(size_t)(idx - N_USERS - M_ITEMS) * K_DIM + k];
            s  += val * b;
            sq += val * b * b;
        }
    }
    pu[sl][k] = u; pt[sl][k] = t; ps[sl][k] = s; psq[sl][k] = sq;
    __syncthreads();

    // Reduce slices per k, form the 5 per-k products
    if (tid < K_DIM) {
        float U = 0.0f, T = 0.0f, S = 0.0f, SQ = 0.0f;
        #pragma unroll
        for (int j = 0; j < 8; ++j) {
            U += pu[j][tid]; T += pt[j][tid]; S += ps[j][tid]; SQ += psq[j][tid];
        }
        red[0][tid] = U * T;
        red[1][tid] = T * S;
        red[2][tid] = S * S;
        red[3][tid] = U * S;
        red[4][tid] = SQ;
    }
    // fold bias partials into a single slot alongside the tree reduce
    __syncthreads();
    // tree-reduce red[5][128] and sb[256] with the first 128 threads
    if (tid < 128) sb[tid] += sb[tid + 128];
    __syncthreads();
    for (int off = K_DIM / 2; off > 0; off >>= 1) {
        if (tid < off) {
            #pragma unroll
            for (int j = 0; j < 5; ++j) red[j][tid] += red[j][tid + off];
            sb[tid] += sb[tid + off];
        }
        __syncthreads();
    }

    if (tid == 0) {
        const float ut = red[0][0], tb = red[1][0], ss = red[2][0],
                    ub = red[3][0], sqs = red[4][0];
        const float bs = 0.5f * (ss - sqs);
        // GAMMA = (1,1,1,1)
        float y = w0[0] + sb[0] + ut + tb + bs + ub;
        float z = y * delta[0];
        // -log_sigmoid(z) = softplus(-z), numerically stable
        float a = -z;
        out[0] = fmaxf(a, 0.0f) + log1pf(expf(-fabsf(a)));
    }
}

extern "C" void kernel_launch(void* const* d_in, const int* in_sizes, int n_in,
                              void* d_out, int out_size, void* d_ws, size_t ws_size,
                              hipStream_t stream) {
    const float* x      = (const float*)d_in[0];
    const float* delta  = (const float*)d_in[1];
    // d_in[2] = pmi, unused by the reference
    const float* w0     = (const float*)d_in[3];
    const float* w_bias = (const float*)d_in[4];
    const float* uV     = (const float*)d_in[5];
    const float* tV     = (const float*)d_in[6];
    const float* bV     = (const float*)d_in[7];
    float* out = (float*)d_out;

    int*   counts = (int*)d_ws;
    int*   gidx   = (int*)((char*)d_ws + 4096);
    float* gval   = (float*)((char*)d_ws + 4096 + SCAN_BLOCKS * SLOTS * sizeof(int));

    scan_kernel<<<SCAN_BLOCKS, SCAN_T, 0, stream>>>(x, counts, gidx, gval);
    finish_kernel<<<1, 1024, 0, stream>>>(counts, gidx, gval, w0, delta,
                                          w_bias, uV, tV, bV, out);
}